// Round 11
// baseline (77.287 us; speedup 1.0000x reference)
//
#include <hip/hip_runtime.h>
#include <hip/hip_bf16.h>

typedef short bf16x8 __attribute__((ext_vector_type(8)));
typedef float f32x4  __attribute__((ext_vector_type(4)));

union fragU { f32x4 f; bf16x8 b; uint4 q; uint u[4]; };

// RNE f32->bf16 (pre-kernels only)
__device__ inline ushort f2bf(float f) {
    union { float f; uint u; } v; v.f = f;
    uint r = (v.u + 0x7FFFu + ((v.u >> 16) & 1u)) >> 16;
    return (ushort)r;
}
__device__ inline uint packbf(float a, float b) {
    return (uint)f2bf(a) | ((uint)f2bf(b) << 16);
}
// hot path: single-instruction RNE pack
__device__ inline uint cvtpk(float lo, float hi) {
    uint r;
    asm("v_cvt_pk_bf16_f32 %0, %1, %2" : "=v"(r) : "v"(lo), "v"(hi));
    return r;
}

// ---- pre-kernel A: pack x rows: [f0..f4, 1.0, 0, 0] bf16; row N = zeros ----
__global__ __launch_bounds__(256) void pack_x_kernel(
    const float* __restrict__ x, uint4* __restrict__ xp, int N)
{
    int i = blockIdx.x * blockDim.x + threadIdx.x;
    if (i > N) return;
    uint4 o = {0u, 0u, 0u, 0u};
    if (i < N) {
        const float* r = x + (size_t)i * 5;
        o.x = packbf(r[0], r[1]);
        o.y = packbf(r[2], r[3]);
        o.z = packbf(r[4], 1.0f);   // slot 5 = 1.0 : bias enabler
    }
    xp[i] = o;
}

// ---- pre-kernel B: per-lane fragment table (14 chunks x 64 lanes x 16B) ----
// chunk 0..3  : W1^T A-frags (EF k-layout, b1 at k=5, h1[50]:=1 enabler)
// chunk 4..11 : W2^T A-frags, formal-K perm sigma; hid1==50 := b2
// chunk 12..13: W3 A-frags (row 0 only), same sigma on k
__global__ __launch_bounds__(64) void pack_w_kernel(
    const float* __restrict__ W1, const float* __restrict__ b1,
    const float* __restrict__ W2, const float* __restrict__ b2,
    const float* __restrict__ W3, uint4* __restrict__ tab)
{
    const int lane = threadIdx.x;       // one wave
    const int c = lane & 15;
    const int g = lane >> 4;

    union { ushort s[8]; uint4 q; } u;
    #pragma unroll
    for (int mt = 0; mt < 4; ++mt) {
        #pragma unroll
        for (int d = 0; d < 8; ++d) {
            int k = 8 * g + d;
            int j = 16 * mt + c;
            float v = 0.f;
            if (j < 50) {
                if (k < 5)                 v = W1[k * 50 + j];
                else if (k == 5)           v = b1[j];
                else if (k >= 8 && k < 13) v = W1[(k - 3) * 50 + j];
            } else if (j == 50 && k == 5)  v = 1.0f;
            u.s[d] = f2bf(v);
        }
        tab[mt * 64 + lane] = u.q;
    }
    #pragma unroll
    for (int t = 0; t < 2; ++t) {
        #pragma unroll
        for (int mt = 0; mt < 4; ++mt) {
            #pragma unroll
            for (int d = 0; d < 8; ++d) {
                int hid1 = 16 * (2 * t + (d >> 2)) + 4 * g + (d & 3);
                int j    = 16 * mt + c;
                float v = 0.f;
                if (j < 50) {
                    if (hid1 < 50)       v = W2[hid1 * 50 + j];
                    else if (hid1 == 50) v = b2[j];
                }
                u.s[d] = f2bf(v);
            }
            tab[(4 + t * 4 + mt) * 64 + lane] = u.q;
        }
    }
    #pragma unroll
    for (int t = 0; t < 2; ++t) {
        #pragma unroll
        for (int d = 0; d < 8; ++d) {
            int hid = 16 * (2 * t + (d >> 2)) + 4 * g + (d & 3);
            float v = (c == 0 && hid < 50) ? W3[hid] : 0.f;
            u.s[d] = f2bf(v);
        }
        tab[(12 + t) * 64 + lane] = u.q;
    }
}

// ---- main: 16 edges/wave (single chain, minimal regs), weights PINNED,
//      2-deep decoupled idx/gather pipeline, no LDS, 4 waves/SIMD target ----
__global__ __launch_bounds__(256, 4) void edge_mlp_mfma9(
    const uint4* __restrict__ xp,
    const uint4* __restrict__ wtab,
    const int* __restrict__ ei,
    const float* __restrict__ b3,
    float* __restrict__ out, int E, int num_tiles)
{
    const int tid  = threadIdx.x;
    const int w    = tid >> 6;
    const int lane = tid & 63;
    const int c    = lane & 15;
    const int g    = lane >> 4;
    const int G    = gridDim.x;

    // one-time coalesced fragment load, then PIN in registers (opaque to
    // optimizer -> no re-load, no remat)
    fragU w1f[4], w2f[8], w3f[2];
    #pragma unroll
    for (int i = 0; i < 4; ++i) w1f[i].q = wtab[i * 64 + lane];
    #pragma unroll
    for (int i = 0; i < 8; ++i) w2f[i].q = wtab[(4 + i) * 64 + lane];
    #pragma unroll
    for (int i = 0; i < 2; ++i) w3f[i].q = wtab[(12 + i) * 64 + lane];
    asm volatile("" :
        "+v"(w1f[0].f), "+v"(w1f[1].f), "+v"(w1f[2].f), "+v"(w1f[3].f),
        "+v"(w2f[0].f), "+v"(w2f[1].f), "+v"(w2f[2].f), "+v"(w2f[3].f),
        "+v"(w2f[4].f), "+v"(w2f[5].f), "+v"(w2f[6].f), "+v"(w2f[7].f),
        "+v"(w3f[0].f), "+v"(w3f[1].f));

    const float b3s = b3[0];

    // index for tile bt_ (clamped): lane (c, g<2) owns one edge's node index
    auto LOAD_IDX = [&](int bt_) -> int {
        int bc = (bt_ < num_tiles) ? bt_ : (num_tiles - 1);
        int v = 0;
        if (g < 2) {
            int e = bc * 64 + w * 16 + c;
            if (e >= E) e = 0;
            v = ei[(size_t)g * (size_t)E + (size_t)e];
        }
        return v;
    };
    auto GATHER = [&](int idx) -> fragU {
        fragU a;
        uint4 q = {0u, 0u, 0u, 0u};
        if (g < 2) q = xp[idx];
        a.q = q;
        return a;
    };

    int bt = blockIdx.x;
    if (bt >= num_tiles) return;

    // pipeline prologue
    fragU fC = GATHER(LOAD_IDX(bt));
    int idxN = LOAD_IDX(bt + G);

    for (; bt < num_tiles; bt += G) {
        fragU fN = GATHER(idxN);          // address resident -> issue now
        idxN = LOAD_IDX(bt + 2 * G);      // independent, for t+2

        // ---- layer 1 (+b1 folded): h1^T = W1ext^T @ EF^T ----
        f32x4 hT[4];
        #pragma unroll
        for (int mt = 0; mt < 4; ++mt) {
            f32x4 z = {0.f, 0.f, 0.f, 0.f};
            hT[mt] = __builtin_amdgcn_mfma_f32_16x16x32_bf16(w1f[mt].b, fC.b, z, 0, 0, 0);
        }
        // relu + pack -> layer-2 B-frags (sigma baked into W2 frags)
        fragU bB0, bB1;
        #pragma unroll
        for (int mt = 0; mt < 2; ++mt) {
            bB0.u[2*mt]   = cvtpk(fmaxf(hT[mt][0], 0.f),   fmaxf(hT[mt][1], 0.f));
            bB0.u[2*mt+1] = cvtpk(fmaxf(hT[mt][2], 0.f),   fmaxf(hT[mt][3], 0.f));
            bB1.u[2*mt]   = cvtpk(fmaxf(hT[2+mt][0], 0.f), fmaxf(hT[2+mt][1], 0.f));
            bB1.u[2*mt+1] = cvtpk(fmaxf(hT[2+mt][2], 0.f), fmaxf(hT[2+mt][3], 0.f));
        }

        // ---- layer 2 (+b2 folded): h2^T = W2ext^T @ h1^T ----
        f32x4 h2T[4];
        #pragma unroll
        for (int mt = 0; mt < 4; ++mt) {
            f32x4 z = {0.f, 0.f, 0.f, 0.f};
            h2T[mt] = __builtin_amdgcn_mfma_f32_16x16x32_bf16(w2f[mt].b,     bB0.b, z, 0, 0, 0);
            h2T[mt] = __builtin_amdgcn_mfma_f32_16x16x32_bf16(w2f[4 + mt].b, bB1.b, h2T[mt], 0, 0, 0);
        }
        // relu + pack -> layer-3 B-frags (same sigma)
        fragU cB0, cB1;
        #pragma unroll
        for (int mt = 0; mt < 2; ++mt) {
            cB0.u[2*mt]   = cvtpk(fmaxf(h2T[mt][0], 0.f),   fmaxf(h2T[mt][1], 0.f));
            cB0.u[2*mt+1] = cvtpk(fmaxf(h2T[mt][2], 0.f),   fmaxf(h2T[mt][3], 0.f));
            cB1.u[2*mt]   = cvtpk(fmaxf(h2T[2+mt][0], 0.f), fmaxf(h2T[2+mt][1], 0.f));
            cB1.u[2*mt+1] = cvtpk(fmaxf(h2T[2+mt][2], 0.f), fmaxf(h2T[2+mt][3], 0.f));
        }

        // ---- layer 3 as MFMA: C row 0 = W3 . relu(h2) ----
        f32x4 z3 = {0.f, 0.f, 0.f, 0.f};
        f32x4 o3 = __builtin_amdgcn_mfma_f32_16x16x32_bf16(w3f[0].b, cB0.b, z3, 0, 0, 0);
        o3 = __builtin_amdgcn_mfma_f32_16x16x32_bf16(w3f[1].b, cB1.b, o3, 0, 0, 0);

        if (g == 0) {                     // C row 0 -> lanes 0..15, reg 0
            int e = bt * 64 + w * 16 + c;
            if (e < E) {
                float ex = __expf(-(o3[0] + b3s));
                out[e] = __builtin_amdgcn_rcpf(1.f + ex);
            }
        }

        fC = fN;
    }
}

extern "C" void kernel_launch(void* const* d_in, const int* in_sizes, int n_in,
                              void* d_out, int out_size, void* d_ws, size_t ws_size,
                              hipStream_t stream) {
    const float* x  = (const float*)d_in[0];
    const int*   ei = (const int*)d_in[1];
    const float* W1 = (const float*)d_in[2];
    const float* b1 = (const float*)d_in[3];
    const float* W2 = (const float*)d_in[4];
    const float* b2 = (const float*)d_in[5];
    const float* W3 = (const float*)d_in[6];
    const float* b3 = (const float*)d_in[7];
    float* out = (float*)d_out;

    int E = in_sizes[1] / 2;      // edge_index is [2, E]
    int N = in_sizes[0] / 5;      // nodes

    uint4* wtab = (uint4*)d_ws;                    // 14 KB fragment table
    uint4* xp   = (uint4*)((char*)d_ws + 16384);   // (N+1) * 16 B packed x

    pack_w_kernel<<<1, 64, 0, stream>>>(W1, b1, W2, b2, W3, wtab);
    pack_x_kernel<<<(N + 1 + 255) / 256, 256, 0, stream>>>(x, xp, N);

    int num_tiles = (E + 63) / 64;                 // 64 edges per block-tile
    int grid = num_tiles < 2048 ? num_tiles : 2048;
    edge_mlp_mfma9<<<grid, 256, 0, stream>>>(xp, wtab, ei, b3, out, E, num_tiles);
}

// Round 12
// 73.182 us; speedup vs baseline: 1.0561x; 1.0561x over previous
//
#include <hip/hip_runtime.h>
#include <hip/hip_bf16.h>

typedef short bf16x8 __attribute__((ext_vector_type(8)));
typedef float f32x4  __attribute__((ext_vector_type(4)));

union fragU { f32x4 f; bf16x8 b; uint4 q; uint u[4]; };

// RNE f32->bf16 (pre-kernels only)
__device__ inline ushort f2bf(float f) {
    union { float f; uint u; } v; v.f = f;
    uint r = (v.u + 0x7FFFu + ((v.u >> 16) & 1u)) >> 16;
    return (ushort)r;
}
__device__ inline uint packbf(float a, float b) {
    return (uint)f2bf(a) | ((uint)f2bf(b) << 16);
}
// hot path: single-instruction RNE pack
__device__ inline uint cvtpk(float lo, float hi) {
    uint r;
    asm("v_cvt_pk_bf16_f32 %0, %1, %2" : "=v"(r) : "v"(lo), "v"(hi));
    return r;
}

// ---- pre-kernel A: pack x rows: [f0..f4, 1.0, 0, 0] bf16; row N = zeros ----
__global__ __launch_bounds__(256) void pack_x_kernel(
    const float* __restrict__ x, uint4* __restrict__ xp, int N)
{
    int i = blockIdx.x * blockDim.x + threadIdx.x;
    if (i > N) return;
    uint4 o = {0u, 0u, 0u, 0u};
    if (i < N) {
        const float* r = x + (size_t)i * 5;
        o.x = packbf(r[0], r[1]);
        o.y = packbf(r[2], r[3]);
        o.z = packbf(r[4], 1.0f);   // slot 5 = 1.0 : bias enabler
    }
    xp[i] = o;
}

// ---- pre-kernel B: per-lane fragment table (14 chunks x 64 lanes x 16B) ----
// chunk 0..3  : W1^T A-frags (EF k-layout, b1 at k=5, h1[50]:=1 enabler)
// chunk 4..11 : W2^T A-frags, formal-K perm sigma; hid1==50 := b2
// chunk 12..13: W3 A-frags (row 0 only), same sigma on k
__global__ __launch_bounds__(64) void pack_w_kernel(
    const float* __restrict__ W1, const float* __restrict__ b1,
    const float* __restrict__ W2, const float* __restrict__ b2,
    const float* __restrict__ W3, uint4* __restrict__ tab)
{
    const int lane = threadIdx.x;       // one wave
    const int c = lane & 15;
    const int g = lane >> 4;

    union { ushort s[8]; uint4 q; } u;
    #pragma unroll
    for (int mt = 0; mt < 4; ++mt) {
        #pragma unroll
        for (int d = 0; d < 8; ++d) {
            int k = 8 * g + d;
            int j = 16 * mt + c;
            float v = 0.f;
            if (j < 50) {
                if (k < 5)                 v = W1[k * 50 + j];
                else if (k == 5)           v = b1[j];
                else if (k >= 8 && k < 13) v = W1[(k - 3) * 50 + j];
            } else if (j == 50 && k == 5)  v = 1.0f;
            u.s[d] = f2bf(v);
        }
        tab[mt * 64 + lane] = u.q;
    }
    #pragma unroll
    for (int t = 0; t < 2; ++t) {
        #pragma unroll
        for (int mt = 0; mt < 4; ++mt) {
            #pragma unroll
            for (int d = 0; d < 8; ++d) {
                int hid1 = 16 * (2 * t + (d >> 2)) + 4 * g + (d & 3);
                int j    = 16 * mt + c;
                float v = 0.f;
                if (j < 50) {
                    if (hid1 < 50)       v = W2[hid1 * 50 + j];
                    else if (hid1 == 50) v = b2[j];
                }
                u.s[d] = f2bf(v);
            }
            tab[(4 + t * 4 + mt) * 64 + lane] = u.q;
        }
    }
    #pragma unroll
    for (int t = 0; t < 2; ++t) {
        #pragma unroll
        for (int d = 0; d < 8; ++d) {
            int hid = 16 * (2 * t + (d >> 2)) + 4 * g + (d & 3);
            float v = (c == 0 && hid < 50) ? W3[hid] : 0.f;
            u.s[d] = f2bf(v);
        }
        tab[(12 + t) * 64 + lane] = u.q;
    }
}

// ---- main: 16 edges/wave, pinned weights, 4-deep gather pipeline,
//      non-temporal ei/out streams (protect xp residency in L2) ----
__global__ __launch_bounds__(256, 4) void edge_mlp_mfma10(
    const uint4* __restrict__ xp,
    const uint4* __restrict__ wtab,
    const int* __restrict__ ei,
    const float* __restrict__ b3,
    float* __restrict__ out, int E, int num_tiles)
{
    const int tid  = threadIdx.x;
    const int w    = tid >> 6;
    const int lane = tid & 63;
    const int c    = lane & 15;
    const int g    = lane >> 4;
    const int G    = gridDim.x;

    // one-time coalesced fragment load, then PIN in registers
    fragU w1f[4], w2f[8], w3f[2];
    #pragma unroll
    for (int i = 0; i < 4; ++i) w1f[i].q = wtab[i * 64 + lane];
    #pragma unroll
    for (int i = 0; i < 8; ++i) w2f[i].q = wtab[(4 + i) * 64 + lane];
    #pragma unroll
    for (int i = 0; i < 2; ++i) w3f[i].q = wtab[(12 + i) * 64 + lane];
    asm volatile("" :
        "+v"(w1f[0].f), "+v"(w1f[1].f), "+v"(w1f[2].f), "+v"(w1f[3].f),
        "+v"(w2f[0].f), "+v"(w2f[1].f), "+v"(w2f[2].f), "+v"(w2f[3].f),
        "+v"(w2f[4].f), "+v"(w2f[5].f), "+v"(w2f[6].f), "+v"(w2f[7].f),
        "+v"(w3f[0].f), "+v"(w3f[1].f));

    const float b3s = b3[0];

    // index load for tile bt_ (clamped), NON-TEMPORAL (don't pollute L2)
    auto LOAD_IDX = [&](int bt_) -> int {
        int bc = (bt_ < num_tiles) ? bt_ : (num_tiles - 1);
        int v = 0;
        if (g < 2) {
            int e = bc * 64 + w * 16 + c;
            if (e >= E) e = 0;
            v = __builtin_nontemporal_load(&ei[(size_t)g * (size_t)E + (size_t)e]);
        }
        return v;
    };
    // fragment gather (regular cached load -> wants L2 residency)
    auto GATHER = [&](int idx) -> fragU {
        fragU a;
        uint4 q = {0u, 0u, 0u, 0u};
        if (g < 2) q = xp[idx];
        a.q = q;
        return a;
    };

    // compute + store one 16-edge subtile from fragment aX at tile T
    auto COMPUTE = [&](fragU aX, int T) {
        // layer 1 (+b1 folded)
        f32x4 hT[4];
        #pragma unroll
        for (int mt = 0; mt < 4; ++mt) {
            f32x4 z = {0.f, 0.f, 0.f, 0.f};
            hT[mt] = __builtin_amdgcn_mfma_f32_16x16x32_bf16(w1f[mt].b, aX.b, z, 0, 0, 0);
        }
        fragU bB0, bB1;
        #pragma unroll
        for (int mt = 0; mt < 2; ++mt) {
            bB0.u[2*mt]   = cvtpk(fmaxf(hT[mt][0], 0.f),   fmaxf(hT[mt][1], 0.f));
            bB0.u[2*mt+1] = cvtpk(fmaxf(hT[mt][2], 0.f),   fmaxf(hT[mt][3], 0.f));
            bB1.u[2*mt]   = cvtpk(fmaxf(hT[2+mt][0], 0.f), fmaxf(hT[2+mt][1], 0.f));
            bB1.u[2*mt+1] = cvtpk(fmaxf(hT[2+mt][2], 0.f), fmaxf(hT[2+mt][3], 0.f));
        }
        // layer 2 (+b2 folded)
        f32x4 h2T[4];
        #pragma unroll
        for (int mt = 0; mt < 4; ++mt) {
            f32x4 z = {0.f, 0.f, 0.f, 0.f};
            h2T[mt] = __builtin_amdgcn_mfma_f32_16x16x32_bf16(w2f[mt].b,     bB0.b, z, 0, 0, 0);
            h2T[mt] = __builtin_amdgcn_mfma_f32_16x16x32_bf16(w2f[4 + mt].b, bB1.b, h2T[mt], 0, 0, 0);
        }
        fragU cB0, cB1;
        #pragma unroll
        for (int mt = 0; mt < 2; ++mt) {
            cB0.u[2*mt]   = cvtpk(fmaxf(h2T[mt][0], 0.f),   fmaxf(h2T[mt][1], 0.f));
            cB0.u[2*mt+1] = cvtpk(fmaxf(h2T[mt][2], 0.f),   fmaxf(h2T[mt][3], 0.f));
            cB1.u[2*mt]   = cvtpk(fmaxf(h2T[2+mt][0], 0.f), fmaxf(h2T[2+mt][1], 0.f));
            cB1.u[2*mt+1] = cvtpk(fmaxf(h2T[2+mt][2], 0.f), fmaxf(h2T[2+mt][3], 0.f));
        }
        // layer 3 as MFMA: C row 0 = W3 . relu(h2)
        f32x4 z3 = {0.f, 0.f, 0.f, 0.f};
        f32x4 o3 = __builtin_amdgcn_mfma_f32_16x16x32_bf16(w3f[0].b, cB0.b, z3, 0, 0, 0);
        o3 = __builtin_amdgcn_mfma_f32_16x16x32_bf16(w3f[1].b, cB1.b, o3, 0, 0, 0);

        if (g == 0) {                     // C row 0 -> lanes 0..15, reg 0
            int e = T * 64 + w * 16 + c;
            if (e < E) {
                float ex = __expf(-(o3[0] + b3s));
                float sg = __builtin_amdgcn_rcpf(1.f + ex);
                __builtin_nontemporal_store(sg, &out[e]);   // don't evict xp
            }
        }
    };

    int bt = blockIdx.x;
    if (bt >= num_tiles) return;

    // ---- 4-deep pipeline prologue ----
    int idxB[4];
    fragU fB[4];
    #pragma unroll
    for (int p = 0; p < 4; ++p) idxB[p] = LOAD_IDX(bt + p * G);
    #pragma unroll
    for (int p = 0; p < 4; ++p) fB[p] = GATHER(idxB[p]);
    #pragma unroll
    for (int p = 0; p < 4; ++p) idxB[p] = LOAD_IDX(bt + (p + 4) * G);

    // ---- main loop: compute slot p (tile T), refill for T+4G, idx for T+8G.
    //      Each gather's vmcnt wait lands 3 compute-slots after issue. ----
    for (; bt < num_tiles; bt += 4 * G) {
        #pragma unroll
        for (int p = 0; p < 4; ++p) {
            const int T = bt + p * G;
            COMPUTE(fB[p], T);
            fB[p] = GATHER(idxB[p]);               // frags for T+4G
            idxB[p] = LOAD_IDX(bt + (p + 8) * G);  // idx  for T+8G
        }
    }
}

extern "C" void kernel_launch(void* const* d_in, const int* in_sizes, int n_in,
                              void* d_out, int out_size, void* d_ws, size_t ws_size,
                              hipStream_t stream) {
    const float* x  = (const float*)d_in[0];
    const int*   ei = (const int*)d_in[1];
    const float* W1 = (const float*)d_in[2];
    const float* b1 = (const float*)d_in[3];
    const float* W2 = (const float*)d_in[4];
    const float* b2 = (const float*)d_in[5];
    const float* W3 = (const float*)d_in[6];
    const float* b3 = (const float*)d_in[7];
    float* out = (float*)d_out;

    int E = in_sizes[1] / 2;      // edge_index is [2, E]
    int N = in_sizes[0] / 5;      // nodes

    uint4* wtab = (uint4*)d_ws;                    // 14 KB fragment table
    uint4* xp   = (uint4*)((char*)d_ws + 16384);   // (N+1) * 16 B packed x

    pack_w_kernel<<<1, 64, 0, stream>>>(W1, b1, W2, b2, W3, wtab);
    pack_x_kernel<<<(N + 1 + 255) / 256, 256, 0, stream>>>(x, xp, N);

    int num_tiles = (E + 63) / 64;                 // 64 edges per block-tile
    int grid = num_tiles < 2048 ? num_tiles : 2048;
    edge_mlp_mfma10<<<grid, 256, 0, stream>>>(xp, wtab, ei, b3, out, E, num_tiles);
}